// Round 16
// baseline (362.979 us; speedup 1.0000x reference)
//
#include <hip/hip_runtime.h>
#include <hip/hip_bf16.h>

#define Nn 8
#define Cc 64
#define Tt 16
#define Hh 56
#define Ww 56

typedef __bf16 bf16x8 __attribute__((ext_vector_type(8)));
typedef float f32x16 __attribute__((ext_vector_type(16)));
typedef unsigned short u16;
typedef unsigned int u32;

__device__ __forceinline__ u16 f32_to_bf16(float f) {
    u32 u = __float_as_uint(f);
    u32 r = (u + 0x7FFFu + ((u >> 16) & 1u)) >> 16;
    return (u16)r;
}
__device__ __forceinline__ float bf16_to_f32(u16 h) {
    return __uint_as_float(((u32)h) << 16);
}

// async global->LDS, 16B per lane, dst = wave-uniform base + lane*16
__device__ __forceinline__ void gload16(const void* gsrc, void* lds) {
    __builtin_amdgcn_global_load_lds(
        (const __attribute__((address_space(1))) u32*)gsrc,
        (__attribute__((address_space(3))) u32*)lds, 16, 0, 0);
}

// ---------------- P0: weights -> bf16 hi/lo in [tap][co][ci]; +zeros page ----
__global__ __launch_bounds__(256) void prep_w_kernel(
    const float* __restrict__ w1, const float* __restrict__ w2,
    u16* __restrict__ w1h, u16* __restrict__ w1l,
    u16* __restrict__ w2h, u16* __restrict__ w2l,
    u16* __restrict__ zpage)
{
    int idx = blockIdx.x * 256 + threadIdx.x;
    if (idx >= 221184) {                            // zeros page: 256 x 16B = 4KB
        ((uint4*)zpage)[idx - 221184] = make_uint4(0, 0, 0, 0);
        return;
    }
    int conv = idx / 110592;
    int rem  = idx % 110592;
    int tap  = rem >> 12;
    int co   = (rem >> 6) & 63;
    int ci   = rem & 63;
    const float* w = conv ? w2 : w1;
    float v = w[co * 1728 + ci * 27 + tap];
    u16 hi = f32_to_bf16(v);
    u16 lo = f32_to_bf16(v - bf16_to_f32(hi));
    int dst = tap * 4096 + co * 64 + ci;
    if (conv) { w2h[dst] = hi; w2l[dst] = lo; }
    else      { w1h[dst] = hi; w1l[dst] = lo; }
}

// ---------------- P1: x -> xh bf16 in [n][t][h][w][ci] (hi only) ----------------
__global__ __launch_bounds__(256) void split_x_kernel(
    const float* __restrict__ x, u16* __restrict__ xh)
{
    __shared__ float tile[Cc][Hh + 1];
    const int tid = threadIdx.x;
    const int bid = blockIdx.x;           // = (n*Tt + t)*Hh + h
    const int h = bid % Hh;
    const int t = (bid / Hh) % Tt;
    const int n = bid / (Hh * Tt);
    for (int it = 0; it < 14; ++it) {
        int id = it * 256 + tid;
        int ci = id / Ww, w = id % Ww;
        tile[ci][w] = x[(((size_t)(n * Cc + ci) * Tt + t) * Hh + h) * Ww + w];
    }
    __syncthreads();
    const size_t obase = (size_t)bid * (Ww * Cc);
    for (int it = 0; it < 7; ++it) {
        int j = it * 256 + tid;
        int w = j >> 5, ci0 = (j & 31) << 1;
        u16 h0 = f32_to_bf16(tile[ci0][w]);
        u16 h1 = f32_to_bf16(tile[ci0 + 1][w]);
        *(ushort2*)(xh + obase + (size_t)w * Cc + ci0) = make_ushort2(h0, h1);
    }
}

// ---------------- conv kernels ----------------
// A slice: 58 rows (x-pos -1..56) x 64B (32 ci). Chunk fi -> LDS byte fi*16 (LINEAR).
// XOR swizzle on global SOURCE index; reads apply the same XOR.
// 256-thr blocks: 4 waves, each wave computes 2 h-rows (B-frag reads amortized 2x).
#define SLICE_B 3712                  // 58*64
#define A1_BUF  40960                 // 2320 data chunks + pad
#define B1_BUF  36864                 // 9 taps x 4096 (one hl)
#define C1_SMEM (2 * A1_BUF + 2 * B1_BUF)   // 155648 -> 1 block/CU
#define C2_BOFF 40960
#define C2_SMEM 81920                 // 2 blocks/CU

__device__ __forceinline__ const bf16x8* frag_ptr(const char* base, int row, int slot) {
    int col = (slot * 16) ^ (((row >> 1) & 3) << 4);
    return (const bf16x8*)(base + row * 64 + col);
}

// conv1: 2-pass (xh*wh, xh*wl), 32x32x16 MFMA, A+B double-buffered, 12 sub-slabs
__global__ __launch_bounds__(256, 2) void conv1_mfma_kernel(
    const u16* __restrict__ xh,
    const u16* __restrict__ w1h, const u16* __restrict__ w1l,
    const float* __restrict__ b1, const float* __restrict__ e1,
    const u16* __restrict__ zpage, u16* __restrict__ res1)
{
    __shared__ __align__(16) char smem[C1_SMEM];

    const int tid = threadIdx.x;
    const int l = tid & 63, wid = tid >> 6;         // wid 0..3
    const int l31 = l & 31, hi5 = l >> 5;
    const int wbase = tid & ~63;                    // wave-uniform
    const int bid = (blockIdx.x & 7) * 112 + (blockIdx.x >> 3);
    const int hb = bid % 7;
    const int t  = (bid / 7) % Tt;
    const int n  = bid / (7 * Tt);
    const int h0 = hb * 8;

    f32x16 acc[2][2][2] = {};                       // [dh][m][nt]

    // issue A gloads for slab (cih,kd): 2560 chunks (2320 data + pad)
    auto ISSUE_A = [&](int slab, int abuf) {
        char* dst = smem + abuf * A1_BUF;
        const int cih = slab / 3, kd = slab % 3;
        const int td = t + kd - 1;
        const bool tdv = (td >= 0 && td < Tt);
        const size_t tdbase = (size_t)(n * Tt + (tdv ? td : 0)) * ((size_t)Hh * Ww * Cc);
#pragma unroll
        for (int it = 0; it < 10; ++it) {
            int fi = it * 256 + tid;
            int u = fi / 232, c = fi - u * 232;
            int r = c >> 2, slot = c & 3;
            int hh = h0 - 1 + u;
            int slog = slot ^ ((r >> 1) & 3);       // pre-swizzled source
            const u16* src = xh + tdbase
                + ((size_t)hh * Ww + (r - 1)) * Cc + cih * 32 + slog * 8;
            bool valid = tdv & (fi < 2320) & (hh >= 0) & (hh < Hh) & (r >= 1) & (r <= Ww);
            if (!valid) src = zpage;
            gload16(src, dst + (it * 256 + wbase) * 16);
        }
    };
    // issue B gloads for sub-slab (cih,kd,hl): 2304 chunks (exact 9 iters)
    auto ISSUE_B = [&](int sub, int bbuf) {
        char* dst = smem + 2 * A1_BUF + bbuf * B1_BUF;
        const int slab = sub >> 1, hl = sub & 1;
        const int cih = slab / 3, kd = slab % 3;
        const u16* wsrc = hl ? w1l : w1h;
#pragma unroll
        for (int it = 0; it < 9; ++it) {
            int fi = it * 256 + tid;
            int u = fi >> 8, c = fi & 255;
            int co = c >> 2, slot = c & 3;
            int slog = slot ^ ((co >> 1) & 3);
            const u16* src = wsrc + (kd * 9 + u) * 4096 + co * 64 + cih * 32 + slog * 8;
            gload16(src, dst + (it * 256 + wbase) * 16);
        }
    };

    // prologue: prime A0, B0
    ISSUE_A(0, 0);
    ISSUE_B(0, 0);
    asm volatile("s_waitcnt vmcnt(0)" ::: "memory");
    __builtin_amdgcn_s_barrier();
    __builtin_amdgcn_sched_barrier(0);

#pragma unroll 1
    for (int j = 0; j < 12; ++j) {
        // prefetch: next B always; next A when entering new slab (j odd)
        if (j < 11) ISSUE_B(j + 1, (j + 1) & 1);
        if ((j & 1) && (j < 11)) ISSUE_A((j + 1) >> 1, ((j + 1) >> 1) & 1);
        __builtin_amdgcn_sched_barrier(0);
        // compute sub-slab j from A buf (j>>1)&1, B buf j&1
        const char* Acur = smem + (((j >> 1) & 1) * A1_BUF);
        const char* Bcur = smem + 2 * A1_BUF + ((j & 1) * B1_BUF);
#pragma unroll
        for (int kh = 0; kh < 3; ++kh) {
#pragma unroll
            for (int kw = 0; kw < 3; ++kw) {
                const int tap9 = kh * 3 + kw;
                bf16x8 b[2][2];
#pragma unroll
                for (int nt = 0; nt < 2; ++nt)
#pragma unroll
                    for (int kk = 0; kk < 2; ++kk)
                        b[nt][kk] = *frag_ptr(Bcur + tap9 * 4096, l31 + 32 * nt, kk * 2 + hi5);
#pragma unroll
                for (int dh = 0; dh < 2; ++dh) {
                    const char* Ak = Acur + (size_t)(2 * wid + dh + kh) * SLICE_B;
                    bf16x8 a[2][2];
#pragma unroll
                    for (int m = 0; m < 2; ++m)
#pragma unroll
                        for (int kk = 0; kk < 2; ++kk)
                            a[m][kk] = *frag_ptr(Ak, l31 + 32 * m + kw, kk * 2 + hi5);
                    __builtin_amdgcn_s_setprio(1);
#pragma unroll
                    for (int m = 0; m < 2; ++m)
#pragma unroll
                        for (int nt = 0; nt < 2; ++nt)
#pragma unroll
                            for (int kk = 0; kk < 2; ++kk)
                                acc[dh][m][nt] = __builtin_amdgcn_mfma_f32_32x32x16_bf16(
                                    a[m][kk], b[nt][kk], acc[dh][m][nt], 0, 0, 0);
                    __builtin_amdgcn_s_setprio(0);
                }
            }
        }
        __builtin_amdgcn_sched_barrier(0);
        __builtin_amdgcn_s_barrier();               // all waves done reading bufs
        asm volatile("s_waitcnt vmcnt(0)" ::: "memory");  // prefetches landed
        __builtin_amdgcn_s_barrier();
        __builtin_amdgcn_sched_barrier(0);
    }

    // epilogue: bias, BFP quant, relu, store bf16 (exact)
#pragma unroll
    for (int dh = 0; dh < 2; ++dh) {
        const int h = h0 + 2 * wid + dh;
        const size_t rowbase = ((size_t)(n * Tt + t) * Hh + h) * ((size_t)Ww * Cc);
#pragma unroll
        for (int nt = 0; nt < 2; ++nt) {
            int co = 32 * nt + l31;
            float e = e1[co];
            float sc = exp2f(7.0f - e), inv = exp2f(e - 7.0f);
            float bias = b1[co];
#pragma unroll
            for (int m = 0; m < 2; ++m)
#pragma unroll
                for (int reg = 0; reg < 16; ++reg) {
                    int w = 32 * m + (reg & 3) + 8 * (reg >> 2) + 4 * hi5;
                    if (w < Ww) {
                        float v = acc[dh][m][nt][reg] + bias;
                        float q = rintf(v * sc);
                        q = fminf(fmaxf(q, -127.f), 127.f);
                        v = fmaxf(q * inv, 0.0f);
                        res1[rowbase + (size_t)w * Cc + co] = f32_to_bf16(v);
                    }
                }
        }
    }
}

// conv2: single-pass (a.w2h), 32x32x16 MFMA, 80KB LDS -> 2 blocks/CU, wave = 2 h-rows
__global__ __launch_bounds__(256, 2) void conv2_mfma_kernel(
    const u16* __restrict__ a, const u16* __restrict__ w2h,
    const float* __restrict__ b2, const float* __restrict__ e2,
    const float* __restrict__ x, const u16* __restrict__ zpage,
    float* __restrict__ out)
{
    __shared__ __align__(16) char smem[C2_SMEM];
    char* As = smem;
    char* Bs = smem + C2_BOFF;

    const int tid = threadIdx.x;
    const int l = tid & 63, wid = tid >> 6;
    const int l31 = l & 31, hi5 = l >> 5;
    const int wbase = tid & ~63;
    const int bid = (blockIdx.x & 7) * 112 + (blockIdx.x >> 3);
    const int hb = bid % 7;
    const int t  = (bid / 7) % Tt;
    const int n  = bid / (7 * Tt);
    const int h0 = hb * 8;

    f32x16 acc[2][2][2] = {};                       // [dh][m][nt]

#pragma unroll 1
    for (int cih = 0; cih < 2; ++cih) {
#pragma unroll 1
      for (int kd = 0; kd < 3; ++kd) {
        const int td = t + kd - 1;
        if (td < 0 || td >= Tt) continue;
        __builtin_amdgcn_sched_barrier(0);
        __builtin_amdgcn_s_barrier();
        __builtin_amdgcn_sched_barrier(0);
        // stage A: 2320 chunks (10 iters, tail -> pad)
        {
          const size_t tdbase = (size_t)(n * Tt + td) * ((size_t)Hh * Ww * Cc);
#pragma unroll
          for (int it = 0; it < 10; ++it) {
            int fi = it * 256 + tid;
            int u = fi / 232, c = fi - u * 232;
            int r = c >> 2, slot = c & 3;
            int hh = h0 - 1 + u;
            int slog = slot ^ ((r >> 1) & 3);
            const u16* src = a + tdbase
                + ((size_t)hh * Ww + (r - 1)) * Cc + cih * 32 + slog * 8;
            bool valid = (fi < 2320) & (hh >= 0) & (hh < Hh) & (r >= 1) & (r <= Ww);
            if (!valid) src = zpage;
            gload16(src, As + (it * 256 + wbase) * 16);
          }
        }
        // stage B: 2304 chunks (hi only, exact 9 iters)
        {
#pragma unroll
          for (int it = 0; it < 9; ++it) {
            int fi = it * 256 + tid;
            int u = fi >> 8, c = fi & 255;
            int co = c >> 2, slot = c & 3;
            int slog = slot ^ ((co >> 1) & 3);
            const u16* src = w2h + (kd * 9 + u) * 4096 + co * 64 + cih * 32 + slog * 8;
            gload16(src, Bs + (it * 256 + wbase) * 16);
          }
        }
        asm volatile("s_waitcnt vmcnt(0)" ::: "memory");
        __builtin_amdgcn_s_barrier();
        __builtin_amdgcn_sched_barrier(0);
#pragma unroll
        for (int kh = 0; kh < 3; ++kh) {
#pragma unroll
          for (int kw = 0; kw < 3; ++kw) {
            const int tap9 = kh * 3 + kw;
            bf16x8 b[2][2];
#pragma unroll
            for (int nt = 0; nt < 2; ++nt)
#pragma unroll
              for (int kk = 0; kk < 2; ++kk)
                b[nt][kk] = *frag_ptr(Bs + tap9 * 4096, l31 + 32 * nt, kk * 2 + hi5);
#pragma unroll
            for (int dh = 0; dh < 2; ++dh) {
              const char* Ak = As + (size_t)(2 * wid + dh + kh) * SLICE_B;
              bf16x8 a2[2][2];
#pragma unroll
              for (int m = 0; m < 2; ++m)
#pragma unroll
                for (int kk = 0; kk < 2; ++kk)
                  a2[m][kk] = *frag_ptr(Ak, l31 + 32 * m + kw, kk * 2 + hi5);
              __builtin_amdgcn_s_setprio(1);
#pragma unroll
              for (int m = 0; m < 2; ++m)
#pragma unroll
                for (int nt = 0; nt < 2; ++nt)
#pragma unroll
                  for (int kk = 0; kk < 2; ++kk)
                    acc[dh][m][nt] = __builtin_amdgcn_mfma_f32_32x32x16_bf16(
                        a2[m][kk], b[nt][kk], acc[dh][m][nt], 0, 0, 0);
              __builtin_amdgcn_s_setprio(0);
            }
          }
        }
      }
    }
    // epilogue: conv-quant + identity-quant + relu -> f32 out (NCDHW)
#pragma unroll
    for (int dh = 0; dh < 2; ++dh) {
      const int h = h0 + 2 * wid + dh;
#pragma unroll
      for (int nt = 0; nt < 2; ++nt) {
        int co = 32 * nt + l31;
        float e = e2[co];
        float sc = exp2f(7.0f - e), inv = exp2f(e - 7.0f);
        float bias = b2[co];
#pragma unroll
        for (int m = 0; m < 2; ++m)
#pragma unroll
          for (int reg = 0; reg < 16; ++reg) {
            int w = 32 * m + (reg & 3) + 8 * (reg >> 2) + 4 * hi5;
            if (w < Ww) {
              float v = acc[dh][m][nt][reg] + bias;
              float q = rintf(v * sc);
              q = fminf(fmaxf(q, -127.f), 127.f);
              v = q * inv;
              size_t xi = (((size_t)(n * Cc + co) * Tt + t) * Hh + h) * Ww + w;
              float xv = x[xi];
              float qx = rintf(xv * sc);
              qx = fminf(fmaxf(qx, -127.f), 127.f);
              out[xi] = fmaxf(qx * inv + v, 0.0f);
            }
          }
      }
    }
}

extern "C" void kernel_launch(void* const* d_in, const int* in_sizes, int n_in,
                              void* d_out, int out_size, void* d_ws, size_t ws_size,
                              hipStream_t stream) {
    const float* x  = (const float*)d_in[0];
    const float* w1 = (const float*)d_in[1];
    const float* b1 = (const float*)d_in[2];
    const float* w2 = (const float*)d_in[3];
    const float* b2 = (const float*)d_in[4];
    const float* e1 = (const float*)d_in[5];
    const float* e2 = (const float*)d_in[6];

    u16* xh = (u16*)d_out;                 // d_out doubles as xh scratch
    char* ws = (char*)d_ws;
    u16* w1h = (u16*)(ws);
    u16* w1l = (u16*)(ws + 221184);
    u16* w2h = (u16*)(ws + 442368);
    u16* w2l = (u16*)(ws + 663552);
    u16* zpage = (u16*)(ws + 884736);      // 4KB zeros
    u16* res1  = (u16*)(ws + 888832);      // 51.4 MB

    prep_w_kernel<<<865, 256, 0, stream>>>(w1, w2, w1h, w1l, w2h, w2l, zpage);
    split_x_kernel<<<Nn * Tt * Hh, 256, 0, stream>>>(x, xh);
    conv1_mfma_kernel<<<896, 256, 0, stream>>>(xh, w1h, w1l, b1, e1, zpage, res1);
    conv2_mfma_kernel<<<896, 256, 0, stream>>>(res1, w2h, b2, e2, x, zpage, (float*)d_out);
}

// Round 18
// 333.500 us; speedup vs baseline: 1.0884x; 1.0884x over previous
//
#include <hip/hip_runtime.h>
#include <hip/hip_bf16.h>

#define Nn 8
#define Cc 64
#define Tt 16
#define Hh 56
#define Ww 56

typedef __bf16 bf16x8 __attribute__((ext_vector_type(8)));
typedef float f32x16 __attribute__((ext_vector_type(16)));
typedef unsigned short u16;
typedef unsigned int u32;

__device__ __forceinline__ u16 f32_to_bf16(float f) {
    u32 u = __float_as_uint(f);
    u32 r = (u + 0x7FFFu + ((u >> 16) & 1u)) >> 16;
    return (u16)r;
}
__device__ __forceinline__ float bf16_to_f32(u16 h) {
    return __uint_as_float(((u32)h) << 16);
}

// async global->LDS, 16B per lane, dst = wave-uniform base + lane*16
__device__ __forceinline__ void gload16(const void* gsrc, void* lds) {
    __builtin_amdgcn_global_load_lds(
        (const __attribute__((address_space(1))) u32*)gsrc,
        (__attribute__((address_space(3))) u32*)lds, 16, 0, 0);
}

// ---------------- P0: weights -> bf16 hi/lo in [tap][co][ci]; +zeros page ----
__global__ __launch_bounds__(256) void prep_w_kernel(
    const float* __restrict__ w1, const float* __restrict__ w2,
    u16* __restrict__ w1h, u16* __restrict__ w1l,
    u16* __restrict__ w2h, u16* __restrict__ w2l,
    u16* __restrict__ zpage)
{
    int idx = blockIdx.x * 256 + threadIdx.x;
    if (idx >= 221184) {                            // zeros page: 256 x 16B = 4KB
        ((uint4*)zpage)[idx - 221184] = make_uint4(0, 0, 0, 0);
        return;
    }
    int conv = idx / 110592;
    int rem  = idx % 110592;
    int tap  = rem >> 12;
    int co   = (rem >> 6) & 63;
    int ci   = rem & 63;
    const float* w = conv ? w2 : w1;
    float v = w[co * 1728 + ci * 27 + tap];
    u16 hi = f32_to_bf16(v);
    u16 lo = f32_to_bf16(v - bf16_to_f32(hi));
    int dst = tap * 4096 + co * 64 + ci;
    if (conv) { w2h[dst] = hi; w2l[dst] = lo; }
    else      { w1h[dst] = hi; w1l[dst] = lo; }
}

// ---------------- P1: x -> xh bf16 in [n][t][h][w][ci] (hi only) ----------------
__global__ __launch_bounds__(256) void split_x_kernel(
    const float* __restrict__ x, u16* __restrict__ xh)
{
    __shared__ float tile[Cc][Hh + 1];
    const int tid = threadIdx.x;
    const int bid = blockIdx.x;           // = (n*Tt + t)*Hh + h
    const int h = bid % Hh;
    const int t = (bid / Hh) % Tt;
    const int n = bid / (Hh * Tt);
    for (int it = 0; it < 14; ++it) {
        int id = it * 256 + tid;
        int ci = id / Ww, w = id % Ww;
        tile[ci][w] = x[(((size_t)(n * Cc + ci) * Tt + t) * Hh + h) * Ww + w];
    }
    __syncthreads();
    const size_t obase = (size_t)bid * (Ww * Cc);
    for (int it = 0; it < 7; ++it) {
        int j = it * 256 + tid;
        int w = j >> 5, ci0 = (j & 31) << 1;
        u16 h0 = f32_to_bf16(tile[ci0][w]);
        u16 h1 = f32_to_bf16(tile[ci0 + 1][w]);
        *(ushort2*)(xh + obase + (size_t)w * Cc + ci0) = make_ushort2(h0, h1);
    }
}

// ---------------- conv kernels ----------------
// A slice: 58 rows (x-pos -1..56) x 64B (32 ci). Chunk fi -> LDS byte fi*16 (LINEAR).
// XOR swizzle on global SOURCE index; reads apply the same XOR.
// 256-thr blocks, wave = 2 h-rows (dh). Single-buffered A+B = 77824 B -> 2 blocks/CU
// (2 waves/SIMD); staging phase-separated from reads (R9 discipline, no DMA||read
// conflicts within a block); cross-block overlap hides staging.
#define SLICE_B 3712                  // 58*64
#define A1_BUF  40960                 // 2320 data chunks + pad
#define B1_BUF  36864                 // 9 taps x 4096 (one hl)
#define C1_SMEM (A1_BUF + B1_BUF)     // 77824 -> 2 blocks/CU
#define C2_BOFF 40960
#define C2_SMEM 81920                 // 2 blocks/CU

__device__ __forceinline__ const bf16x8* frag_ptr(const char* base, int row, int slot) {
    int col = (slot * 16) ^ (((row >> 1) & 3) << 4);
    return (const bf16x8*)(base + row * 64 + col);
}

// conv1: 2-pass (xh*wh, xh*wl), 32x32x16 MFMA, 12 sub-slabs, stage->bar->compute
__global__ __launch_bounds__(256, 2) void conv1_mfma_kernel(
    const u16* __restrict__ xh,
    const u16* __restrict__ w1h, const u16* __restrict__ w1l,
    const float* __restrict__ b1, const float* __restrict__ e1,
    const u16* __restrict__ zpage, u16* __restrict__ res1)
{
    __shared__ __align__(16) char smem[C1_SMEM];

    const int tid = threadIdx.x;
    const int l = tid & 63, wid = tid >> 6;         // wid 0..3
    const int l31 = l & 31, hi5 = l >> 5;
    const int wbase = tid & ~63;                    // wave-uniform
    const int bid = (blockIdx.x & 7) * 112 + (blockIdx.x >> 3);
    const int hb = bid % 7;
    const int t  = (bid / 7) % Tt;
    const int n  = bid / (7 * Tt);
    const int h0 = hb * 8;

    f32x16 acc[2][2][2] = {};                       // [dh][m][nt]

    // issue A gloads for slab (cih,kd): 2560 chunks (2320 data + pad)
    auto ISSUE_A = [&](int slab) {
        char* dst = smem;
        const int cih = slab / 3, kd = slab % 3;
        const int td = t + kd - 1;
        const bool tdv = (td >= 0 && td < Tt);
        const size_t tdbase = (size_t)(n * Tt + (tdv ? td : 0)) * ((size_t)Hh * Ww * Cc);
#pragma unroll
        for (int it = 0; it < 10; ++it) {
            int fi = it * 256 + tid;
            int u = fi / 232, c = fi - u * 232;
            int r = c >> 2, slot = c & 3;
            int hh = h0 - 1 + u;
            int slog = slot ^ ((r >> 1) & 3);       // pre-swizzled source
            const u16* src = xh + tdbase
                + ((size_t)hh * Ww + (r - 1)) * Cc + cih * 32 + slog * 8;
            bool valid = tdv & (fi < 2320) & (hh >= 0) & (hh < Hh) & (r >= 1) & (r <= Ww);
            if (!valid) src = zpage;
            gload16(src, dst + (it * 256 + wbase) * 16);
        }
    };
    // issue B gloads for sub-slab (cih,kd,hl): 2304 chunks (exact 9 iters)
    auto ISSUE_B = [&](int sub) {
        char* dst = smem + A1_BUF;
        const int slab = sub >> 1, hl = sub & 1;
        const int cih = slab / 3, kd = slab % 3;
        const u16* wsrc = hl ? w1l : w1h;
#pragma unroll
        for (int it = 0; it < 9; ++it) {
            int fi = it * 256 + tid;
            int u = fi >> 8, c = fi & 255;
            int co = c >> 2, slot = c & 3;
            int slog = slot ^ ((co >> 1) & 3);
            const u16* src = wsrc + (kd * 9 + u) * 4096 + co * 64 + cih * 32 + slog * 8;
            gload16(src, dst + (it * 256 + wbase) * 16);
        }
    };

#pragma unroll 1
    for (int j = 0; j < 12; ++j) {
        __builtin_amdgcn_sched_barrier(0);
        __builtin_amdgcn_s_barrier();               // readers of bufs done
        __builtin_amdgcn_sched_barrier(0);
        if ((j & 1) == 0) ISSUE_A(j >> 1);          // A shared by hi/lo sub-slabs
        ISSUE_B(j);
        asm volatile("s_waitcnt vmcnt(0)" ::: "memory");
        __builtin_amdgcn_s_barrier();
        __builtin_amdgcn_sched_barrier(0);
        // compute sub-slab j
        const char* Bcur = smem + A1_BUF;
#pragma unroll
        for (int kh = 0; kh < 3; ++kh) {
#pragma unroll
            for (int kw = 0; kw < 3; ++kw) {
                const int tap9 = kh * 3 + kw;
                bf16x8 b[2][2];
#pragma unroll
                for (int nt = 0; nt < 2; ++nt)
#pragma unroll
                    for (int kk = 0; kk < 2; ++kk)
                        b[nt][kk] = *frag_ptr(Bcur + tap9 * 4096, l31 + 32 * nt, kk * 2 + hi5);
#pragma unroll
                for (int dh = 0; dh < 2; ++dh) {
                    const char* Ak = smem + (size_t)(2 * wid + dh + kh) * SLICE_B;
                    bf16x8 a[2][2];
#pragma unroll
                    for (int m = 0; m < 2; ++m)
#pragma unroll
                        for (int kk = 0; kk < 2; ++kk)
                            a[m][kk] = *frag_ptr(Ak, l31 + 32 * m + kw, kk * 2 + hi5);
                    __builtin_amdgcn_s_setprio(1);
#pragma unroll
                    for (int m = 0; m < 2; ++m)
#pragma unroll
                        for (int nt = 0; nt < 2; ++nt)
#pragma unroll
                            for (int kk = 0; kk < 2; ++kk)
                                acc[dh][m][nt] = __builtin_amdgcn_mfma_f32_32x32x16_bf16(
                                    a[m][kk], b[nt][kk], acc[dh][m][nt], 0, 0, 0);
                    __builtin_amdgcn_s_setprio(0);
                }
            }
        }
    }

    // epilogue: bias, BFP quant, relu, store bf16 (exact)
#pragma unroll
    for (int dh = 0; dh < 2; ++dh) {
        const int h = h0 + 2 * wid + dh;
        const size_t rowbase = ((size_t)(n * Tt + t) * Hh + h) * ((size_t)Ww * Cc);
#pragma unroll
        for (int nt = 0; nt < 2; ++nt) {
            int co = 32 * nt + l31;
            float e = e1[co];
            float sc = exp2f(7.0f - e), inv = exp2f(e - 7.0f);
            float bias = b1[co];
#pragma unroll
            for (int m = 0; m < 2; ++m)
#pragma unroll
                for (int reg = 0; reg < 16; ++reg) {
                    int w = 32 * m + (reg & 3) + 8 * (reg >> 2) + 4 * hi5;
                    if (w < Ww) {
                        float v = acc[dh][m][nt][reg] + bias;
                        float q = rintf(v * sc);
                        q = fminf(fmaxf(q, -127.f), 127.f);
                        v = fmaxf(q * inv, 0.0f);
                        res1[rowbase + (size_t)w * Cc + co] = f32_to_bf16(v);
                    }
                }
        }
    }
}

// conv2: single-pass (a.w2h), 32x32x16 MFMA, 80KB LDS -> 2 blocks/CU, wave = 2 h-rows
__global__ __launch_bounds__(256, 2) void conv2_mfma_kernel(
    const u16* __restrict__ a, const u16* __restrict__ w2h,
    const float* __restrict__ b2, const float* __restrict__ e2,
    const float* __restrict__ x, const u16* __restrict__ zpage,
    float* __restrict__ out)
{
    __shared__ __align__(16) char smem[C2_SMEM];
    char* As = smem;
    char* Bs = smem + C2_BOFF;

    const int tid = threadIdx.x;
    const int l = tid & 63, wid = tid >> 6;
    const int l31 = l & 31, hi5 = l >> 5;
    const int wbase = tid & ~63;
    const int bid = (blockIdx.x & 7) * 112 + (blockIdx.x >> 3);
    const int hb = bid % 7;
    const int t  = (bid / 7) % Tt;
    const int n  = bid / (7 * Tt);
    const int h0 = hb * 8;

    f32x16 acc[2][2][2] = {};                       // [dh][m][nt]

#pragma unroll 1
    for (int cih = 0; cih < 2; ++cih) {
#pragma unroll 1
      for (int kd = 0; kd < 3; ++kd) {
        const int td = t + kd - 1;
        if (td < 0 || td >= Tt) continue;
        __builtin_amdgcn_sched_barrier(0);
        __builtin_amdgcn_s_barrier();
        __builtin_amdgcn_sched_barrier(0);
        // stage A: 2320 chunks (10 iters, tail -> pad)
        {
          const size_t tdbase = (size_t)(n * Tt + td) * ((size_t)Hh * Ww * Cc);
#pragma unroll
          for (int it = 0; it < 10; ++it) {
            int fi = it * 256 + tid;
            int u = fi / 232, c = fi - u * 232;
            int r = c >> 2, slot = c & 3;
            int hh = h0 - 1 + u;
            int slog = slot ^ ((r >> 1) & 3);
            const u16* src = a + tdbase
                + ((size_t)hh * Ww + (r - 1)) * Cc + cih * 32 + slog * 8;
            bool valid = (fi < 2320) & (hh >= 0) & (hh < Hh) & (r >= 1) & (r <= Ww);
            if (!valid) src = zpage;
            gload16(src, As + (it * 256 + wbase) * 16);
          }
        }
        // stage B: 2304 chunks (hi only, exact 9 iters)
        {
#pragma unroll
          for (int it = 0; it < 9; ++it) {
            int fi = it * 256 + tid;
            int u = fi >> 8, c = fi & 255;
            int co = c >> 2, slot = c & 3;
            int slog = slot ^ ((co >> 1) & 3);
            const u16* src = w2h + (kd * 9 + u) * 4096 + co * 64 + cih * 32 + slog * 8;
            gload16(src, Bs + (it * 256 + wbase) * 16);
          }
        }
        asm volatile("s_waitcnt vmcnt(0)" ::: "memory");
        __builtin_amdgcn_s_barrier();
        __builtin_amdgcn_sched_barrier(0);
#pragma unroll
        for (int kh = 0; kh < 3; ++kh) {
#pragma unroll
          for (int kw = 0; kw < 3; ++kw) {
            const int tap9 = kh * 3 + kw;
            bf16x8 b[2][2];
#pragma unroll
            for (int nt = 0; nt < 2; ++nt)
#pragma unroll
              for (int kk = 0; kk < 2; ++kk)
                b[nt][kk] = *frag_ptr(Bs + tap9 * 4096, l31 + 32 * nt, kk * 2 + hi5);
#pragma unroll
            for (int dh = 0; dh < 2; ++dh) {
              const char* Ak = As + (size_t)(2 * wid + dh + kh) * SLICE_B;
              bf16x8 a2[2][2];
#pragma unroll
              for (int m = 0; m < 2; ++m)
#pragma unroll
                for (int kk = 0; kk < 2; ++kk)
                  a2[m][kk] = *frag_ptr(Ak, l31 + 32 * m + kw, kk * 2 + hi5);
              __builtin_amdgcn_s_setprio(1);
#pragma unroll
              for (int m = 0; m < 2; ++m)
#pragma unroll
                for (int nt = 0; nt < 2; ++nt)
#pragma unroll
                  for (int kk = 0; kk < 2; ++kk)
                    acc[dh][m][nt] = __builtin_amdgcn_mfma_f32_32x32x16_bf16(
                        a2[m][kk], b[nt][kk], acc[dh][m][nt], 0, 0, 0);
              __builtin_amdgcn_s_setprio(0);
            }
          }
        }
      }
    }
    // epilogue: conv-quant + identity-quant + relu -> f32 out (NCDHW)
#pragma unroll
    for (int dh = 0; dh < 2; ++dh) {
      const int h = h0 + 2 * wid + dh;
#pragma unroll
      for (int nt = 0; nt < 2; ++nt) {
        int co = 32 * nt + l31;
        float e = e2[co];
        float sc = exp2f(7.0f - e), inv = exp2f(e - 7.0f);
        float bias = b2[co];
#pragma unroll
        for (int m = 0; m < 2; ++m)
#pragma unroll
          for (int reg = 0; reg < 16; ++reg) {
            int w = 32 * m + (reg & 3) + 8 * (reg >> 2) + 4 * hi5;
            if (w < Ww) {
              float v = acc[dh][m][nt][reg] + bias;
              float q = rintf(v * sc);
              q = fminf(fmaxf(q, -127.f), 127.f);
              v = q * inv;
              size_t xi = (((size_t)(n * Cc + co) * Tt + t) * Hh + h) * Ww + w;
              float xv = x[xi];
              float qx = rintf(xv * sc);
              qx = fminf(fmaxf(qx, -127.f), 127.f);
              out[xi] = fmaxf(qx * inv + v, 0.0f);
            }
          }
      }
    }
}

extern "C" void kernel_launch(void* const* d_in, const int* in_sizes, int n_in,
                              void* d_out, int out_size, void* d_ws, size_t ws_size,
                              hipStream_t stream) {
    const float* x  = (const float*)d_in[0];
    const float* w1 = (const float*)d_in[1];
    const float* b1 = (const float*)d_in[2];
    const float* w2 = (const float*)d_in[3];
    const float* b2 = (const float*)d_in[4];
    const float* e1 = (const float*)d_in[5];
    const float* e2 = (const float*)d_in[6];

    u16* xh = (u16*)d_out;                 // d_out doubles as xh scratch
    char* ws = (char*)d_ws;
    u16* w1h = (u16*)(ws);
    u16* w1l = (u16*)(ws + 221184);
    u16* w2h = (u16*)(ws + 442368);
    u16* w2l = (u16*)(ws + 663552);
    u16* zpage = (u16*)(ws + 884736);      // 4KB zeros
    u16* res1  = (u16*)(ws + 888832);      // 51.4 MB

    prep_w_kernel<<<865, 256, 0, stream>>>(w1, w2, w1h, w1l, w2h, w2l, zpage);
    split_x_kernel<<<Nn * Tt * Hh, 256, 0, stream>>>(x, xh);
    conv1_mfma_kernel<<<896, 256, 0, stream>>>(xh, w1h, w1l, b1, e1, zpage, res1);
    conv2_mfma_kernel<<<896, 256, 0, stream>>>(res1, w2h, b2, e2, x, zpage, (float*)d_out);
}